// Round 9
// baseline (2517.478 us; speedup 1.0000x reference)
//
#include <hip/hip_runtime.h>
#include <hip/hip_bf16.h>

#define S_ 8
#define B_ 32
#define T_ 512
#define I_ 256
#define H_ 512
#define O_ 32

typedef __attribute__((ext_vector_type(8))) short short8;
typedef __attribute__((ext_vector_type(4))) float float4_;

__device__ __forceinline__ unsigned short f2bf(float f) {
    unsigned u = __float_as_uint(f);
    u = (u + 0x7fffu + ((u >> 16) & 1u)) >> 16;   // RNE
    return (unsigned short)u;
}
__device__ __forceinline__ short8 cvt2(float4_ a, float4_ b) {
    short8 r;
    r[0]=(short)f2bf(a[0]); r[1]=(short)f2bf(a[1]); r[2]=(short)f2bf(a[2]); r[3]=(short)f2bf(a[3]);
    r[4]=(short)f2bf(b[0]); r[5]=(short)f2bf(b[1]); r[6]=(short)f2bf(b[2]); r[7]=(short)f2bf(b[3]);
    return r;
}
__device__ __forceinline__ short8 load_cvt8(const float* p) {
    return cvt2(*reinterpret_cast<const float4_*>(p), *reinterpret_cast<const float4_*>(p + 4));
}

// PROVEN transport: sc0 sc1 -> device coherence point (LLC). Loads valid only
// after s_waitcnt vmcnt(0); flag polls touch exactly one cacheline.
__device__ __forceinline__ short8 ld16c(const unsigned short* p) {
    short8 v;
    asm volatile("global_load_dwordx4 %0, %1, off sc0 sc1" : "=v"(v) : "v"(p) : "memory");
    return v;
}
__device__ __forceinline__ unsigned ldu32c(const unsigned* p) {
    unsigned v;
    asm volatile("global_load_dword %0, %1, off sc0 sc1" : "=v"(v) : "v"(p) : "memory");
    return v;
}
__device__ __forceinline__ void st16c(unsigned short* p, short8 v) {
    asm volatile("global_store_dwordx4 %0, %1, off sc0 sc1" :: "v"(p), "v"(v) : "memory");
}
__device__ __forceinline__ void stu32c(unsigned* p, unsigned v) {
    asm volatile("global_store_dword %0, %1, off sc0 sc1" :: "v"(p), "v"(v) : "memory");
}
__device__ __forceinline__ void vm0() {
    asm volatile("s_waitcnt vmcnt(0)" ::: "memory");
    __builtin_amdgcn_sched_barrier(0);   // rule #18
}

// ws layout (bytes):
//   [0, 524288)        : h bf16 double buffer [2][S][B][H]
//   [524288, 540672)   : hbar fp32 [S][H]
//   [540672, 544768)   : flags uint [S][2][64]  (256B per (s,m) group; idx j)
//   [544768, 546816)   : done counters, uint per seq, 256B stride
#define WS_NEED 546816

#define MFMA_ __builtin_amdgcn_mfma_f32_16x16x32_bf16

__global__ __launch_bounds__(256, 1)
void zgru_persistent(const float* __restrict__ x, const int* __restrict__ lens,
                     const float* __restrict__ Wih, const float* __restrict__ Whh,
                     const float* __restrict__ bih, const float* __restrict__ bhh,
                     const float* __restrict__ Wout, const float* __restrict__ bout,
                     float* __restrict__ out,
                     unsigned short* __restrict__ hbuf, float* __restrict__ hbar,
                     unsigned* __restrict__ flags, unsigned* __restrict__ done_ctr)
{
    const int tid  = threadIdx.x;
    const int wg   = blockIdx.x;
    const int s    = wg & 7;         // round-robin -> seq co-located, L2-friendly x
    const int j    = wg >> 3;        // hidden-col group: cols [16j, 16j+16)
    const int wid  = tid >> 6;
    const int lane = tid & 63;
    const int m    = wid >> 1;       // batch half (rows 16m..16m+15)
    const int kh   = wid & 1;        // K half
    const int lrow = lane & 15;
    const int lgrp = lane >> 4;

    const int len = lens[s];

    // ---- LDS (weights now live in registers; LDS only for exchange) -----
    __shared__ float4_ xch[2][4][64];              // [m][gate][lane] partials
    __shared__ __align__(16) unsigned short hsh[2][16 * 24];  // transpose staging
    __shared__ unsigned fxch[2];                   // kh1 -> kh0 tokens per m
    __shared__ unsigned last_flag;
    __shared__ float red[8][32];

    if (tid < 2) fxch[tid] = 0;

    // ---- persistent weight fragments: 36 NAMED short8 (144 VGPRs) -------
    const int gr  = 16 * j + lrow;
    const int khk = 256 * kh;        // W_hh K-half offset
    const int khi = 128 * kh;        // W_ih K-half offset
    const int lg8 = 8 * lgrp;

    short8 bhR0,bhR1,bhR2,bhR3,bhR4,bhR5,bhR6,bhR7;
    short8 bhZ0,bhZ1,bhZ2,bhZ3,bhZ4,bhZ5,bhZ6,bhZ7;
    short8 bhN0,bhN1,bhN2,bhN3,bhN4,bhN5,bhN6,bhN7;
    short8 bxR0,bxR1,bxR2,bxR3, bxZ0,bxZ1,bxZ2,bxZ3, bxN0,bxN1,bxN2,bxN3;

#define LDBH(kc) \
    bhR##kc = load_cvt8(Whh + (size_t)(gr          ) * H_ + khk + 32*kc + lg8); \
    bhZ##kc = load_cvt8(Whh + (size_t)(gr +     H_ ) * H_ + khk + 32*kc + lg8); \
    bhN##kc = load_cvt8(Whh + (size_t)(gr + 2 * H_ ) * H_ + khk + 32*kc + lg8);
    LDBH(0) LDBH(1) LDBH(2) LDBH(3) LDBH(4) LDBH(5) LDBH(6) LDBH(7)
#undef LDBH
#define LDBX(kc) \
    bxR##kc = load_cvt8(Wih + (size_t)(gr          ) * I_ + khi + 32*kc + lg8); \
    bxZ##kc = load_cvt8(Wih + (size_t)(gr +     H_ ) * I_ + khi + 32*kc + lg8); \
    bxN##kc = load_cvt8(Wih + (size_t)(gr + 2 * H_ ) * I_ + khi + 32*kc + lg8);
    LDBX(0) LDBX(1) LDBX(2) LDBX(3)
#undef LDBX
    // Opaque pass: values now originate from asm -> cannot be rematerialized
    // by re-running the load+cvt chains inside the loop.
    asm volatile("" : "+v"(bhR0),"+v"(bhR1),"+v"(bhR2),"+v"(bhR3),
                      "+v"(bhR4),"+v"(bhR5),"+v"(bhR6),"+v"(bhR7));
    asm volatile("" : "+v"(bhZ0),"+v"(bhZ1),"+v"(bhZ2),"+v"(bhZ3),
                      "+v"(bhZ4),"+v"(bhZ5),"+v"(bhZ6),"+v"(bhZ7));
    asm volatile("" : "+v"(bhN0),"+v"(bhN1),"+v"(bhN2),"+v"(bhN3),
                      "+v"(bhN4),"+v"(bhN5),"+v"(bhN6),"+v"(bhN7));
    asm volatile("" : "+v"(bxR0),"+v"(bxR1),"+v"(bxR2),"+v"(bxR3),
                      "+v"(bxZ0),"+v"(bxZ1),"+v"(bxZ2),"+v"(bxZ3),
                      "+v"(bxN0),"+v"(bxN1),"+v"(bxN2),"+v"(bxN3));

    const int gcol   = 16 * j + lrow;
    const float bsR  = bih[gcol] + bhh[gcol];
    const float bsZ  = bih[H_ + gcol] + bhh[H_ + gcol];
    const float biN  = bih[2 * H_ + gcol];
    const float bhN_ = bhh[2 * H_ + gcol];

    __syncthreads();   // fxch ready

    float h[4] = {0.f, 0.f, 0.f, 0.f};

    const size_t HBUF = (size_t)S_ * B_ * H_;
    const int arow = 16 * m + lrow;
    const float* xlane = x + ((size_t)s * B_ + arow) * T_ * I_ + khi + lg8;
    const unsigned short* hrow = hbuf + ((size_t)s * B_ + arow) * H_ + khk + lg8;
    unsigned short* hwrow = hbuf + ((size_t)s * B_ + 16 * m) * H_ + 16 * j;
    const unsigned* fl = flags + (size_t)(s * 2 + m) * 64;
    unsigned* myflag   = flags + (size_t)(s * 2 + m) * 64 + j;

    // prime x(0)
    float4_ xq00,xq01,xq10,xq11,xq20,xq21,xq30,xq31;
    {
        const float* xp = xlane;
#define LDXR(kc) \
        xq##kc##0 = *reinterpret_cast<const float4_*>(xp + 32*kc); \
        xq##kc##1 = *reinterpret_cast<const float4_*>(xp + 32*kc + 4);
        LDXR(0) LDXR(1) LDXR(2) LDXR(3)
#undef LDXR
    }

    for (int t = 0; t < len; ++t) {
        // ---- x part from prefetched regs (implicit waitcnt via cvt use) --
        short8 ax0 = cvt2(xq00, xq01), ax1 = cvt2(xq10, xq11);
        short8 ax2 = cvt2(xq20, xq21), ax3 = cvt2(xq30, xq31);
        float4_ aR = {0,0,0,0}, aZ = {0,0,0,0}, aNX = {0,0,0,0};
#define XMF(kc) \
        aR  = MFMA_(ax##kc, bxR##kc, aR,  0, 0, 0); \
        aZ  = MFMA_(ax##kc, bxZ##kc, aZ,  0, 0, 0); \
        aNX = MFMA_(ax##kc, bxN##kc, aNX, 0, 0, 0);
        XMF(0) XMF(1) XMF(2) XMF(3)
#undef XMF

        // ---- per-(s,m) barrier: 32 producer flags, one line --------------
        if (t > 0) {
            const unsigned tgt = (unsigned)t;
            for (int it = 0; it < (1 << 16); ++it) {
                unsigned fv = ldu32c(fl + (lane & 31));
                vm0();
                if (__ballot(fv >= tgt) == ~0ull) break;
            }
        }

        // ---- h A-fragments (only h loads outstanding here) ---------------
        const unsigned short* hr = hrow + (size_t)(t & 1) * HBUF;
        short8 ah0,ah1,ah2,ah3,ah4,ah5,ah6,ah7;
#define LDH(kc) ah##kc = ld16c(hr + 32*kc);
        LDH(0) LDH(1) LDH(2) LDH(3) LDH(4) LDH(5) LDH(6) LDH(7)
#undef LDH
        vm0();

        float4_ aNH = {0,0,0,0};
#define HMF(kc) \
        aR  = MFMA_(ah##kc, bhR##kc, aR,  0, 0, 0); \
        aZ  = MFMA_(ah##kc, bhZ##kc, aZ,  0, 0, 0); \
        aNH = MFMA_(ah##kc, bhN##kc, aNH, 0, 0, 0);
        HMF(0) HMF(1) HMF(2) HMF(3) HMF(4) HMF(5) HMF(6) HMF(7)
#undef HMF

        if (kh == 1) {   // hand partials to kh==0 via LDS + release token
            xch[m][0][lane] = aR;
            xch[m][1][lane] = aZ;
            xch[m][2][lane] = aNH;
            xch[m][3][lane] = aNX;
            __hip_atomic_store(&fxch[m], (unsigned)(t + 1),
                               __ATOMIC_RELEASE, __HIP_MEMORY_SCOPE_WORKGROUP);
        } else {         // kh==0: merge, gates, coalesced publish, flag
            for (int it = 0; it < (1 << 20); ++it) {
                if (__hip_atomic_load(&fxch[m], __ATOMIC_ACQUIRE,
                                      __HIP_MEMORY_SCOPE_WORKGROUP) >= (unsigned)(t + 1)) break;
            }
            __builtin_amdgcn_sched_barrier(0);
            aR  += xch[m][0][lane];
            aZ  += xch[m][1][lane];
            aNH += xch[m][2][lane];
            aNX += xch[m][3][lane];

            unsigned short* hs = &hsh[m][0];
            #pragma unroll
            for (int i = 0; i < 4; ++i) {
                const float pr = aR[i] + bsR;
                const float pz = aZ[i] + bsZ;
                const float r = 1.f / (1.f + __expf(-pr));
                const float z = 1.f / (1.f + __expf(-pz));
                const float pn = aNX[i] + biN + r * (aNH[i] + bhN_);
                const float e = __expf(-2.f * fabsf(pn));
                float n = (1.f - e) / (1.f + e);
                n = copysignf(n, pn);
                h[i] = z * (h[i] - n) + n;
                hs[(4 * lgrp + i) * 24 + lrow] = f2bf(h[i]);   // transpose stage
            }
            asm volatile("s_waitcnt lgkmcnt(0)" ::: "memory");
            __builtin_amdgcn_sched_barrier(0);
            unsigned short* hw = hwrow + (size_t)((t + 1) & 1) * HBUF;
            if (lane < 32) {   // 16B/lane coalesced publish of [16x16] tile
                const int row = lane >> 1, cc = lane & 1;
                short8 v = *reinterpret_cast<const short8*>(&hs[row * 24 + cc * 8]);
                st16c(hw + (size_t)row * H_ + cc * 8, v);
            }
            vm0();   // drains ONLY the publish stores (x-refill comes after)
            if (lane == 0) stu32c(myflag, (unsigned)(t + 1));
        }

        // ---- x refill for t+1: issued last, hides under flag RTT + poll --
        {
            const int tn = (t + 1 < len) ? (t + 1) : t;
            const float* xp = xlane + (size_t)tn * I_;
#define LDXR(kc) \
            xq##kc##0 = *reinterpret_cast<const float4_*>(xp + 32*kc); \
            xq##kc##1 = *reinterpret_cast<const float4_*>(xp + 32*kc + 4);
            LDXR(0) LDXR(1) LDXR(2) LDXR(3)
#undef LDXR
        }
    }

    // ---- hbar[s][col] = sum_b h -----------------------------------------
    float s4 = h[0] + h[1] + h[2] + h[3];
    s4 += __shfl_xor(s4, 16);
    s4 += __shfl_xor(s4, 32);
    if (kh == 0 && lgrp == 0)
        atomicAdd(&hbar[(size_t)s * H_ + gcol], s4);   // device-scope

    __syncthreads();   // drains atomics before done signal
    if (tid == 0) {
        unsigned old = __hip_atomic_fetch_add(&done_ctr[s * 64], 1u,
                                              __ATOMIC_RELAXED, __HIP_MEMORY_SCOPE_AGENT);
        last_flag = (old == 31u) ? 1u : 0u;
    }
    __syncthreads();
    if (last_flag) {   // last WG of this sequence computes the output row
        const int o = tid & 31;
        const int p = tid >> 5;
        float acc = 0.f;
        const float* hb = hbar + (size_t)s * H_;
        const float* wr = Wout + (size_t)o * H_;
        for (int hh = 64 * p; hh < 64 * p + 64; ++hh) {
            float hv = __hip_atomic_load(&hb[hh], __ATOMIC_RELAXED, __HIP_MEMORY_SCOPE_AGENT);
            acc += hv * wr[hh];
        }
        red[p][o] = acc;
        __syncthreads();
        if (tid < 32) {
            float v = 0.f;
            #pragma unroll
            for (int q = 0; q < 8; ++q) v += red[q][tid];
            out[s * O_ + tid] = v * (1.f / 32.f) + bout[tid];
        }
    }
}

extern "C" void kernel_launch(void* const* d_in, const int* in_sizes, int n_in,
                              void* d_out, int out_size, void* d_ws, size_t ws_size,
                              hipStream_t stream) {
    (void)in_sizes; (void)n_in; (void)out_size; (void)ws_size;
    const float* x    = (const float*)d_in[0];
    const int*   lens = (const int*)d_in[1];
    const float* Wih  = (const float*)d_in[2];
    const float* Whh  = (const float*)d_in[3];
    const float* bih  = (const float*)d_in[4];
    const float* bhh  = (const float*)d_in[5];
    const float* Wout = (const float*)d_in[6];
    const float* bout = (const float*)d_in[7];
    float* out = (float*)d_out;

    char* wsc = (char*)d_ws;
    unsigned short* hbuf = (unsigned short*)wsc;
    float*    hbar  = (float*)(wsc + 524288);
    unsigned* flags = (unsigned*)(wsc + 540672);
    unsigned* dctr  = (unsigned*)(wsc + 544768);

    hipMemsetAsync(d_ws, 0, WS_NEED, stream);

    zgru_persistent<<<dim3(256), dim3(256), 0, stream>>>(
        x, lens, Wih, Whh, bih, bhh, Wout, bout, out, hbuf, hbar, flags, dctr);
}

// Round 10
// 2486.810 us; speedup vs baseline: 1.0123x; 1.0123x over previous
//
#include <hip/hip_runtime.h>
#include <hip/hip_bf16.h>

#define S_ 8
#define B_ 32
#define T_ 512
#define I_ 256
#define H_ 512
#define O_ 32

typedef __attribute__((ext_vector_type(8))) short short8;
typedef __attribute__((ext_vector_type(4))) float float4_;

__device__ __forceinline__ unsigned short f2bf(float f) {
    unsigned u = __float_as_uint(f);
    u = (u + 0x7fffu + ((u >> 16) & 1u)) >> 16;   // RNE
    return (unsigned short)u;
}
__device__ __forceinline__ short8 cvt2(float4_ a, float4_ b) {
    short8 r;
    r[0]=(short)f2bf(a[0]); r[1]=(short)f2bf(a[1]); r[2]=(short)f2bf(a[2]); r[3]=(short)f2bf(a[3]);
    r[4]=(short)f2bf(b[0]); r[5]=(short)f2bf(b[1]); r[6]=(short)f2bf(b[2]); r[7]=(short)f2bf(b[3]);
    return r;
}
__device__ __forceinline__ short8 load_cvt8(const float* p) {
    return cvt2(*reinterpret_cast<const float4_*>(p), *reinterpret_cast<const float4_*>(p + 4));
}

// PROVEN transport: sc0 sc1 -> device coherence point (LLC). Loads valid only
// after s_waitcnt vmcnt(0); flag polls touch exactly one cacheline.
__device__ __forceinline__ short8 ld16c(const unsigned short* p) {
    short8 v;
    asm volatile("global_load_dwordx4 %0, %1, off sc0 sc1" : "=v"(v) : "v"(p) : "memory");
    return v;
}
__device__ __forceinline__ unsigned ldu32c(const unsigned* p) {
    unsigned v;
    asm volatile("global_load_dword %0, %1, off sc0 sc1" : "=v"(v) : "v"(p) : "memory");
    return v;
}
__device__ __forceinline__ void st16c(unsigned short* p, short8 v) {
    asm volatile("global_store_dwordx4 %0, %1, off sc0 sc1" :: "v"(p), "v"(v) : "memory");
}
__device__ __forceinline__ void stu32c(unsigned* p, unsigned v) {
    asm volatile("global_store_dword %0, %1, off sc0 sc1" :: "v"(p), "v"(v) : "memory");
}
__device__ __forceinline__ void vm0() {
    asm volatile("s_waitcnt vmcnt(0)" ::: "memory");
    __builtin_amdgcn_sched_barrier(0);   // rule #18
}

// ws layout (bytes):
//   [0, 524288)        : h bf16 double buffer [2][S][B][H]
//   [524288, 540672)   : hbar fp32 [S][H]
//   [540672, 544768)   : flags uint [S][2][64]  (256B per (s,m) group; idx j)
//   [544768, 546816)   : done counters, uint per seq, 256B stride
#define WS_NEED 546816

#define MFMA_ __builtin_amdgcn_mfma_f32_16x16x32_bf16

__global__ __launch_bounds__(256, 1)
void zgru_persistent(const float* __restrict__ x, const int* __restrict__ lens,
                     const float* __restrict__ Wih, const float* __restrict__ Whh,
                     const float* __restrict__ bih, const float* __restrict__ bhh,
                     const float* __restrict__ Wout, const float* __restrict__ bout,
                     float* __restrict__ out,
                     unsigned short* __restrict__ hbuf, float* __restrict__ hbar,
                     unsigned* __restrict__ flags, unsigned* __restrict__ done_ctr)
{
    const int tid  = threadIdx.x;
    const int wg   = blockIdx.x;
    const int s    = wg & 7;         // round-robin -> seq co-located, L2-friendly x
    const int j    = wg >> 3;        // hidden-col group: cols [16j, 16j+16)
    const int wid  = tid >> 6;
    const int lane = tid & 63;
    const int m    = wid >> 1;       // batch half (rows 16m..16m+15)
    const int kh   = wid & 1;        // K half
    const int lrow = lane & 15;
    const int lgrp = lane >> 4;

    const int len = lens[s];

    // ---- LDS ------------------------------------------------------------
    __shared__ unsigned short whh_lds[48 * 512];   // W_hh bf16 B-fragments (48KB)
    __shared__ unsigned short wih_lds[24 * 512];   // W_ih bf16 B-fragments (24KB)
    __shared__ float4_ xch[2][4][64];              // [m][gate][lane] partials
    __shared__ __align__(16) unsigned short hsh[2][16 * 24];  // transpose staging
    __shared__ unsigned fxch[2];                   // kh1 -> kh0 tokens per m
    __shared__ unsigned last_flag;
    __shared__ float red[8][32];

    // ---- fill W_hh fragments (blk = khb*24 + g*8 + kc) -------------------
    for (int gi = tid; gi < 48 * 64; gi += 256) {
        const int blk = gi >> 6, ln = gi & 63;
        const int khb = blk / 24, rem = blk % 24;
        const int g = rem >> 3, kc = rem & 7;
        const int lg = ln >> 4, lc = ln & 15;
        const float* src = Whh + (size_t)(g * H_ + 16 * j + lc) * H_
                         + 256 * khb + 32 * kc + 8 * lg;
        *reinterpret_cast<short8*>(&whh_lds[(size_t)blk * 512 + ln * 8]) = load_cvt8(src);
    }
    // ---- fill W_ih fragments (blk = khb*12 + g*4 + kc) -------------------
    for (int gi = tid; gi < 24 * 64; gi += 256) {
        const int blk = gi >> 6, ln = gi & 63;
        const int khb = blk / 12, rem = blk % 12;
        const int g = rem >> 2, kc = rem & 3;
        const int lg = ln >> 4, lc = ln & 15;
        const float* src = Wih + (size_t)(g * H_ + 16 * j + lc) * I_
                         + 128 * khb + 32 * kc + 8 * lg;
        *reinterpret_cast<short8*>(&wih_lds[(size_t)blk * 512 + ln * 8]) = load_cvt8(src);
    }
    if (tid < 2) fxch[tid] = 0;

    const int gcol   = 16 * j + lrow;
    const float bsR  = bih[gcol] + bhh[gcol];
    const float bsZ  = bih[H_ + gcol] + bhh[H_ + gcol];
    const float biN  = bih[2 * H_ + gcol];
    const float bhN_ = bhh[2 * H_ + gcol];

    __syncthreads();   // whh_lds + wih_lds + fxch ready

    // ---- W_hh fragments: read once from LDS, live in registers (96 VGPR) -
    short8 bh[24];     // q = g*8 + kc
    #pragma unroll
    for (int q = 0; q < 24; ++q)
        bh[q] = *reinterpret_cast<const short8*>(&whh_lds[(size_t)(kh * 24 + q) * 512 + lane * 8]);

    float h[4] = {0.f, 0.f, 0.f, 0.f};

    const size_t HBUF = (size_t)S_ * B_ * H_;
    const int arow = 16 * m + lrow;
    const float* xlane = x + ((size_t)s * B_ + arow) * T_ * I_ + 128 * kh + 8 * lgrp;
    const unsigned short* hrow = hbuf + ((size_t)s * B_ + arow) * H_ + 256 * kh + 8 * lgrp;
    unsigned short* hwrow = hbuf + ((size_t)s * B_ + 16 * m) * H_ + 16 * j;
    const unsigned* fl = flags + (size_t)(s * 2 + m) * 64;
    unsigned* myflag   = flags + (size_t)(s * 2 + m) * 64 + j;

    // prime x(0)
    float4_ xq00,xq01,xq10,xq11,xq20,xq21,xq30,xq31;
    {
        const float* xp = xlane;
#define LDXR(kc) \
        xq##kc##0 = *reinterpret_cast<const float4_*>(xp + 32*kc); \
        xq##kc##1 = *reinterpret_cast<const float4_*>(xp + 32*kc + 4);
        LDXR(0) LDXR(1) LDXR(2) LDXR(3)
#undef LDXR
    }

    for (int t = 0; t < len; ++t) {
        // ---- consume x(t) from prefetch regs (waits last refill) ---------
        short8 ax0 = cvt2(xq00, xq01), ax1 = cvt2(xq10, xq11);
        short8 ax2 = cvt2(xq20, xq21), ax3 = cvt2(xq30, xq31);

        // ---- refill x(t+1) immediately: in flight across x-MFMAs + poll --
        // (poll's vmcnt(0) waits flag-RTT and x-HBM CONCURRENTLY)
        {
            const int tn = (t + 1 < len) ? (t + 1) : t;
            const float* xp = xlane + (size_t)tn * I_;
#define LDXR(kc) \
            xq##kc##0 = *reinterpret_cast<const float4_*>(xp + 32*kc); \
            xq##kc##1 = *reinterpret_cast<const float4_*>(xp + 32*kc + 4);
            LDXR(0) LDXR(1) LDXR(2) LDXR(3)
#undef LDXR
        }

        // ---- x-part MFMAs, W_ih fragments from LDS -----------------------
        float4_ aR = {0,0,0,0}, aZ = {0,0,0,0}, aNX = {0,0,0,0};
#define XMF(kc) { \
        short8 bR = *reinterpret_cast<const short8*>(&wih_lds[(size_t)(kh*12 +      kc) * 512 + lane * 8]); \
        short8 bZ = *reinterpret_cast<const short8*>(&wih_lds[(size_t)(kh*12 +  4 + kc) * 512 + lane * 8]); \
        short8 bN = *reinterpret_cast<const short8*>(&wih_lds[(size_t)(kh*12 +  8 + kc) * 512 + lane * 8]); \
        aR  = MFMA_(ax##kc, bR, aR,  0, 0, 0); \
        aZ  = MFMA_(ax##kc, bZ, aZ,  0, 0, 0); \
        aNX = MFMA_(ax##kc, bN, aNX, 0, 0, 0); }
        XMF(0) XMF(1) XMF(2) XMF(3)
#undef XMF

        // ---- per-(s,m) barrier: 32 producer flags, one line --------------
        if (t > 0) {
            const unsigned tgt = (unsigned)t;
            for (int it = 0; it < (1 << 16); ++it) {
                unsigned fv = ldu32c(fl + (lane & 31));
                vm0();
                if (__ballot(fv >= tgt) == ~0ull) break;
            }
        }

        // ---- h A-fragments (x refill already drained by poll) ------------
        const unsigned short* hr = hrow + (size_t)(t & 1) * HBUF;
        short8 ah0,ah1,ah2,ah3,ah4,ah5,ah6,ah7;
#define LDH(kc) ah##kc = ld16c(hr + 32*kc);
        LDH(0) LDH(1) LDH(2) LDH(3) LDH(4) LDH(5) LDH(6) LDH(7)
#undef LDH
        vm0();

        float4_ aNH = {0,0,0,0};
#define HMF(kc) \
        aR  = MFMA_(ah##kc, bh[kc     ], aR,  0, 0, 0); \
        aZ  = MFMA_(ah##kc, bh[kc +  8], aZ,  0, 0, 0); \
        aNH = MFMA_(ah##kc, bh[kc + 16], aNH, 0, 0, 0);
        HMF(0) HMF(1) HMF(2) HMF(3) HMF(4) HMF(5) HMF(6) HMF(7)
#undef HMF

        if (kh == 1) {   // hand partials to kh==0 via LDS + release token
            xch[m][0][lane] = aR;
            xch[m][1][lane] = aZ;
            xch[m][2][lane] = aNH;
            xch[m][3][lane] = aNX;
            __hip_atomic_store(&fxch[m], (unsigned)(t + 1),
                               __ATOMIC_RELEASE, __HIP_MEMORY_SCOPE_WORKGROUP);
        } else {         // kh==0: merge, gates, coalesced publish, flag
            for (int it = 0; it < (1 << 20); ++it) {
                if (__hip_atomic_load(&fxch[m], __ATOMIC_ACQUIRE,
                                      __HIP_MEMORY_SCOPE_WORKGROUP) >= (unsigned)(t + 1)) break;
            }
            __builtin_amdgcn_sched_barrier(0);
            aR  += xch[m][0][lane];
            aZ  += xch[m][1][lane];
            aNH += xch[m][2][lane];
            aNX += xch[m][3][lane];

            unsigned short* hs = &hsh[m][0];
            #pragma unroll
            for (int i = 0; i < 4; ++i) {
                const float pr = aR[i] + bsR;
                const float pz = aZ[i] + bsZ;
                const float r = 1.f / (1.f + __expf(-pr));
                const float z = 1.f / (1.f + __expf(-pz));
                const float pn = aNX[i] + biN + r * (aNH[i] + bhN_);
                const float e = __expf(-2.f * fabsf(pn));
                float n = (1.f - e) / (1.f + e);
                n = copysignf(n, pn);
                h[i] = z * (h[i] - n) + n;
                hs[(4 * lgrp + i) * 24 + lrow] = f2bf(h[i]);   // transpose stage
            }
            asm volatile("s_waitcnt lgkmcnt(0)" ::: "memory");
            __builtin_amdgcn_sched_barrier(0);
            unsigned short* hw = hwrow + (size_t)((t + 1) & 1) * HBUF;
            if (lane < 32) {   // 16B/lane coalesced publish of [16x16] tile
                const int row = lane >> 1, cc = lane & 1;
                short8 v = *reinterpret_cast<const short8*>(&hs[row * 24 + cc * 8]);
                st16c(hw + (size_t)row * H_ + cc * 8, v);
            }
            vm0();   // publish at coherence point (x refill long complete)
            if (lane == 0) stu32c(myflag, (unsigned)(t + 1));
        }
    }

    // ---- hbar[s][col] = sum_b h -----------------------------------------
    float s4 = h[0] + h[1] + h[2] + h[3];
    s4 += __shfl_xor(s4, 16);
    s4 += __shfl_xor(s4, 32);
    if (kh == 0 && lgrp == 0)
        atomicAdd(&hbar[(size_t)s * H_ + gcol], s4);   // device-scope

    __syncthreads();   // drains atomics before done signal
    if (tid == 0) {
        unsigned old = __hip_atomic_fetch_add(&done_ctr[s * 64], 1u,
                                              __ATOMIC_RELAXED, __HIP_MEMORY_SCOPE_AGENT);
        last_flag = (old == 31u) ? 1u : 0u;
    }
    __syncthreads();
    if (last_flag) {   // last WG of this sequence computes the output row
        const int o = tid & 31;
        const int p = tid >> 5;
        float acc = 0.f;
        const float* hb = hbar + (size_t)s * H_;
        const float* wr = Wout + (size_t)o * H_;
        for (int hh = 64 * p; hh < 64 * p + 64; ++hh) {
            float hv = __hip_atomic_load(&hb[hh], __ATOMIC_RELAXED, __HIP_MEMORY_SCOPE_AGENT);
            acc += hv * wr[hh];
        }
        red[p][o] = acc;
        __syncthreads();
        if (tid < 32) {
            float v = 0.f;
            #pragma unroll
            for (int q = 0; q < 8; ++q) v += red[q][tid];
            out[s * O_ + tid] = v * (1.f / 32.f) + bout[tid];
        }
    }
}

extern "C" void kernel_launch(void* const* d_in, const int* in_sizes, int n_in,
                              void* d_out, int out_size, void* d_ws, size_t ws_size,
                              hipStream_t stream) {
    (void)in_sizes; (void)n_in; (void)out_size; (void)ws_size;
    const float* x    = (const float*)d_in[0];
    const int*   lens = (const int*)d_in[1];
    const float* Wih  = (const float*)d_in[2];
    const float* Whh  = (const float*)d_in[3];
    const float* bih  = (const float*)d_in[4];
    const float* bhh  = (const float*)d_in[5];
    const float* Wout = (const float*)d_in[6];
    const float* bout = (const float*)d_in[7];
    float* out = (float*)d_out;

    char* wsc = (char*)d_ws;
    unsigned short* hbuf = (unsigned short*)wsc;
    float*    hbar  = (float*)(wsc + 524288);
    unsigned* flags = (unsigned*)(wsc + 540672);
    unsigned* dctr  = (unsigned*)(wsc + 544768);

    hipMemsetAsync(d_ws, 0, WS_NEED, stream);

    zgru_persistent<<<dim3(256), dim3(256), 0, stream>>>(
        x, lens, Wih, Whh, bih, bhh, Wout, bout, out, hbuf, hbar, flags, dctr);
}